// Round 9
// baseline (219.213 us; speedup 1.0000x reference)
//
#include <hip/hip_runtime.h>
#include <stdint.h>

// ---- problem constants ----
#define S_LEN   2048
#define HIDDEN  768
#define NHEADS  12
#define QKV_LD  2304   // fused q|k|v row stride (elements)
#define NW      589824 // 768*768

// MEASUREMENT ROUND: each MFMA kernel repeats its body REP times (idempotent)
// so it exceeds the ~40us harness fill dispatches and surfaces in rocprof
// top-5 with real counters. Revert REP to 1 next round.
#define REP 8

typedef __attribute__((ext_vector_type(8))) short short8;
typedef __attribute__((ext_vector_type(4))) float f32x4;

typedef const __attribute__((address_space(1))) void* gas_ptr;
typedef __attribute__((address_space(3))) void* las_ptr;

__device__ __forceinline__ short f2b(float f) {
    union { float f; uint32_t u; } v; v.f = f;
    uint32_t u = v.u;
    uint32_t r = (u + 0x7FFFu + ((u >> 16) & 1u)) >> 16;
    return (short)r;
}

// ---------------- all f32 -> bf16 converts in one launch ----------------
__global__ __launch_bounds__(256)
void convert_all(const float* __restrict__ X,
                 const float* __restrict__ Wq, const float* __restrict__ Wk,
                 const float* __restrict__ Wv, const float* __restrict__ Wo,
                 short* __restrict__ Xb, short* __restrict__ Wqkvb,
                 short* __restrict__ Wob) {
    int b = blockIdx.x;
    const float* src;
    short* dst;
    int i;
    if (b < 1536) {
        src = X; dst = Xb; i = b * 1024 + threadIdx.x * 4;
    } else {
        int wb = (b - 1536) / 576, lb = (b - 1536) % 576;
        src = wb == 0 ? Wq : wb == 1 ? Wk : wb == 2 ? Wv : Wo;
        dst = wb < 3 ? Wqkvb + wb * NW : Wob;
        i = lb * 1024 + threadIdx.x * 4;
    }
    float4 v = *(const float4*)(src + i);
    *(short4*)(dst + i) = make_short4(f2b(v.x), f2b(v.y), f2b(v.z), f2b(v.w));
}

// ========== bf16 GEMM, 64x128 tile, BK=64, dbuf, global_load_lds ==========
// (exact R6-proven structure, body wrapped in REP loop for profiling)
template<int OUT_BF16>
__device__ __forceinline__ void gemm64x128(const short* __restrict__ A,
    const short* __restrict__ B, void* __restrict__ Cv,
    int bm, int bn, int ldc) {
    __shared__ short sA[2][64 * 64];     // 8KB per buf
    __shared__ short sB[2][128 * 64];    // 16KB per buf  (total 48KB)

    const int tid = threadIdx.x, lane = tid & 63, w = tid >> 6;
    const int wr = w >> 1, wc = w & 1;

    auto stage = [&](int buf, int k0) {
        #pragma unroll
        for (int c = 0; c < 2; ++c) {
            int r = w * 16 + c * 8 + (lane >> 3);
            int scb = ((lane & 7) * 16) ^ ((r & 7) << 4);
            const char* gp = (const char*)(A + (size_t)(bm * 64 + r) * 768 + k0) + scb;
            __builtin_amdgcn_global_load_lds((gas_ptr)gp,
                (las_ptr)((char*)&sA[buf][0] + w * 2048 + c * 1024), 16, 0, 0);
        }
        #pragma unroll
        for (int c = 0; c < 4; ++c) {
            int r = w * 32 + c * 8 + (lane >> 3);
            int scb = ((lane & 7) * 16) ^ ((r & 7) << 4);
            const char* gp = (const char*)(B + (size_t)(bn * 128 + r) * 768 + k0) + scb;
            __builtin_amdgcn_global_load_lds((gas_ptr)gp,
                (las_ptr)((char*)&sB[buf][0] + w * 4096 + c * 1024), 16, 0, 0);
        }
    };

    for (int rep = 0; rep < REP; ++rep) {
        f32x4 acc[2][4] = {};
        stage(0, 0);
        __syncthreads();
        int cur = 0;
        for (int t = 0; t < 12; ++t) {
            if (t < 11) stage(cur ^ 1, (t + 1) * 64);
            #pragma unroll
            for (int kh = 0; kh < 2; ++kh) {
                const int kb = kh * 64 + ((lane >> 4) << 4);
                short8 av[2], bv[4];
                #pragma unroll
                for (int mi = 0; mi < 2; ++mi) {
                    int row = wr * 32 + mi * 16 + (lane & 15);
                    av[mi] = *(const short8*)((const char*)&sA[cur][0] + row * 128 + (kb ^ ((row & 7) << 4)));
                }
                #pragma unroll
                for (int ni = 0; ni < 4; ++ni) {
                    int row = wc * 64 + ni * 16 + (lane & 15);
                    bv[ni] = *(const short8*)((const char*)&sB[cur][0] + row * 128 + (kb ^ ((row & 7) << 4)));
                }
                #pragma unroll
                for (int mi = 0; mi < 2; ++mi)
                    #pragma unroll
                    for (int ni = 0; ni < 4; ++ni)
                        acc[mi][ni] = __builtin_amdgcn_mfma_f32_16x16x32_bf16(
                            av[mi], bv[ni], acc[mi][ni], 0, 0, 0);
            }
            __syncthreads();
            cur ^= 1;
        }

        const int crow0 = bm * 64 + wr * 32;
        const int ccol0 = bn * 128 + wc * 64;
        #pragma unroll
        for (int mi = 0; mi < 2; ++mi)
            #pragma unroll
            for (int ni = 0; ni < 4; ++ni)
                #pragma unroll
                for (int r = 0; r < 4; ++r) {
                    int grow = crow0 + mi * 16 + ((lane >> 4) << 2) + r;
                    int gcol = ccol0 + ni * 16 + (lane & 15);
                    if (OUT_BF16)
                        ((short*)Cv)[(size_t)grow * ldc + gcol] = f2b(acc[mi][ni][r]);
                    else
                        ((float*)Cv)[(size_t)grow * ldc + gcol] = acc[mi][ni][r];
                }
        __syncthreads();   // all C-writes/LDS reads done before re-staging buf0
    }
}

// Kernel 1: QKV = Xb @ Wqkvb^T. M=2048,N=2304 -> 32x18 = 576 blocks (8*72).
__global__ __launch_bounds__(256)
void gemm_qkv(const short* __restrict__ Xb, const short* __restrict__ Wqkvb,
              short* __restrict__ C) {
    const int bid = blockIdx.x;
    const int sw = (bid & 7) * 72 + (bid >> 3);   // bijective XCD chunking
    gemm64x128<1>(Xb, Wqkvb, C, sw / 18, sw % 18, QKV_LD);
}

// Kernel 3: out = Attnb @ Wob^T. M=2048,N=768 -> 32x6 = 192 blocks (8*24).
__global__ __launch_bounds__(256)
void gemm_out(const short* __restrict__ A, const short* __restrict__ Wob,
              float* __restrict__ C) {
    const int bid = blockIdx.x;
    const int sw = (bid & 7) * 24 + (bid >> 3);
    gemm64x128<0>(A, Wob, C, sw / 6, sw % 6, HIDDEN);
}

// ================= Kernel 2: MFMA sliding-window attention ===================
__global__ __launch_bounds__(256)
void attn_mfma(const short* __restrict__ QKV, short* __restrict__ O) {
    __shared__ short sK[128 * 64];       // [kt][d]  swz, 16KB
    __shared__ short sVt[64 * 128];      // [d][kt]  swz, 16KB
    __shared__ short sP[4][16 * 128];    // per-wave [q][kt] swz, 16KB

    const int bid = blockIdx.x;                 // 384 = 8*48
    const int task = (bid & 7) * 48 + (bid >> 3);
    const int h = task % NHEADS;
    const int s0 = (task / NHEADS) * 64;
    const int tid = threadIdx.x, lane = tid & 63, w = tid >> 6;

    for (int rep = 0; rep < REP; ++rep) {
        __syncthreads();   // WAR guard: prior rep's LDS reads done before re-stage

        #pragma unroll
        for (int c = 0; c < 4; ++c) {
            int r = (w * 4 + c) * 8 + (lane >> 3);
            int gr = s0 - 64 + r; if (gr < 0) gr = 0;
            int scb = ((lane & 7) * 16) ^ ((r & 7) << 4);
            const char* gp = (const char*)(QKV + (size_t)gr * QKV_LD + 768 + h * 64) + scb;
            __builtin_amdgcn_global_load_lds((gas_ptr)gp,
                (las_ptr)((char*)sK + (w * 4 + c) * 1024), 16, 0, 0);
        }
        {   // V transposed: thread = (4 keys, 8 dims) -> 8x ds_write_b64
            const int d0 = (tid & 7) * 8;
            const int kbase = (tid >> 3) * 4;
            short8 v[4];
            #pragma unroll
            for (int i = 0; i < 4; ++i) {
                int gr = s0 - 64 + kbase + i; if (gr < 0) gr = 0;
                v[i] = *(const short8*)(QKV + (size_t)gr * QKV_LD + 1536 + h * 64 + d0);
            }
            #pragma unroll
            for (int j = 0; j < 8; ++j) {
                int row = d0 + j;
                int b = row * 256 + ((kbase * 2) ^ ((row & 7) << 4));
                *(short4*)((char*)sVt + b) = make_short4(v[0][j], v[1][j], v[2][j], v[3][j]);
            }
        }
        const int qrow = w * 16 + (lane & 15);
        short8 qf[2];
        #pragma unroll
        for (int kk = 0; kk < 2; ++kk)
            qf[kk] = *(const short8*)(QKV + (size_t)(s0 + qrow) * QKV_LD + h * 64
                                      + kk * 32 + ((lane >> 4) << 3));
        __syncthreads();

        f32x4 s_acc[8];
        #pragma unroll
        for (int ct = 0; ct < 8; ++ct) {
            s_acc[ct] = (f32x4){0.f, 0.f, 0.f, 0.f};
            int krow = ct * 16 + (lane & 15);
            #pragma unroll
            for (int kk = 0; kk < 2; ++kk) {
                int cb = kk * 64 + ((lane >> 4) << 4);
                short8 kf = *(const short8*)((const char*)sK + krow * 128 + (cb ^ ((krow & 7) << 4)));
                s_acc[ct] = __builtin_amdgcn_mfma_f32_16x16x32_bf16(qf[kk], kf, s_acc[ct], 0, 0, 0);
            }
        }

        const int kcol = lane & 15;
        const int qb = w * 16 + ((lane >> 4) << 2);
        float p[8][4];
        #pragma unroll
        for (int r = 0; r < 4; ++r) {
            int q = qb + r;
            float m = -1e30f;
            #pragma unroll
            for (int ct = 0; ct < 8; ++ct) {
                int kt = ct * 16 + kcol;
                bool valid = (kt > q) && (kt <= q + 64) && (s0 + kt >= 64);
                float sc = valid ? s_acc[ct][r] * 0.125f : -1e30f;
                p[ct][r] = sc;
                m = fmaxf(m, sc);
            }
            #pragma unroll
            for (int off = 1; off < 16; off <<= 1) m = fmaxf(m, __shfl_xor(m, off));
            float sm = 0.f;
            #pragma unroll
            for (int ct = 0; ct < 8; ++ct) {
                float e = __expf(p[ct][r] - m);
                p[ct][r] = e;
                sm += e;
            }
            #pragma unroll
            for (int off = 1; off < 16; off <<= 1) sm += __shfl_xor(sm, off);
            float inv = 1.f / sm;
            #pragma unroll
            for (int ct = 0; ct < 8; ++ct) p[ct][r] *= inv;
        }

        #pragma unroll
        for (int ct = 0; ct < 8; ++ct)
            #pragma unroll
            for (int r = 0; r < 4; ++r) {
                int row = ((lane >> 4) << 2) + r;
                int b = row * 256 + (((ct * 16 + kcol) * 2) ^ ((row & 7) << 4));
                *(short*)((char*)&sP[w][0] + b) = f2b(p[ct][r]);
            }

        short8 pf[4];
        #pragma unroll
        for (int kk = 0; kk < 4; ++kk) {
            int row = lane & 15;
            int cb = kk * 64 + ((lane >> 4) << 4);
            pf[kk] = *(const short8*)((const char*)&sP[w][0] + row * 256 + (cb ^ ((row & 7) << 4)));
        }
        f32x4 o_acc[4];
        #pragma unroll
        for (int nt = 0; nt < 4; ++nt) {
            o_acc[nt] = (f32x4){0.f, 0.f, 0.f, 0.f};
            #pragma unroll
            for (int kk = 0; kk < 4; ++kk) {
                int vrow = nt * 16 + (lane & 15);
                int cb = kk * 64 + ((lane >> 4) << 4);
                short8 vf = *(const short8*)((const char*)sVt + vrow * 256 + (cb ^ ((vrow & 7) << 4)));
                o_acc[nt] = __builtin_amdgcn_mfma_f32_16x16x32_bf16(pf[kk], vf, o_acc[nt], 0, 0, 0);
            }
        }

        #pragma unroll
        for (int nt = 0; nt < 4; ++nt)
            #pragma unroll
            for (int r = 0; r < 4; ++r) {
                int q = s0 + qb + r;
                int dcol = h * 64 + nt * 16 + (lane & 15);
                O[(size_t)q * HIDDEN + dcol] = f2b(o_acc[nt][r]);
            }
    }
}

// ---------------- launcher ----------------
extern "C" void kernel_launch(void* const* d_in, const int* in_sizes, int n_in,
                              void* d_out, int out_size, void* d_ws, size_t ws_size,
                              hipStream_t stream) {
    const float* X  = (const float*)d_in[0];
    const float* Wq = (const float*)d_in[1];
    const float* Wk = (const float*)d_in[2];
    const float* Wv = (const float*)d_in[3];
    const float* Wo = (const float*)d_in[4];
    float* out = (float*)d_out;

    char* ws = (char*)d_ws;
    short* Xb    = (short*)ws;                   // 2048*768   bf16
    short* Wqkvb = (short*)(ws + 3145728);       // 2304*768   bf16
    short* Wob   = (short*)(ws + 6684672);       // 768*768    bf16
    short* QKVb  = (short*)(ws + 7864320);       // 2048*2304  bf16
    short* Attnb = (short*)(ws + 17301504);      // 2048*768   bf16

    convert_all<<<1536 + 4 * 576, 256, 0, stream>>>(X, Wq, Wk, Wv, Wo, Xb, Wqkvb, Wob);
    gemm_qkv<<<576, 256, 0, stream>>>(Xb, Wqkvb, QKVb);
    attn_mfma<<<384, 256, 0, stream>>>(QKVb, Attnb);
    gemm_out<<<192, 256, 0, stream>>>(Attnb, Wob, out);
}

// Round 10
// 49.810 us; speedup vs baseline: 4.4010x; 4.4010x over previous
//
#include <hip/hip_runtime.h>
#include <stdint.h>

// ---- problem constants ----
#define S_LEN   2048
#define HIDDEN  768
#define NHEADS  12
#define QKV_LD  2304   // fused q|k|v row stride (elements)
#define NW      589824 // 768*768

typedef __attribute__((ext_vector_type(8))) short short8;
typedef __attribute__((ext_vector_type(4))) float f32x4;

typedef const __attribute__((address_space(1))) void* gas_ptr;
typedef __attribute__((address_space(3))) void* las_ptr;

__device__ __forceinline__ short f2b(float f) {
    union { float f; uint32_t u; } v; v.f = f;
    uint32_t u = v.u;
    uint32_t r = (u + 0x7FFFu + ((u >> 16) & 1u)) >> 16;
    return (short)r;
}

// ---------------- f32 -> bf16 converts: grid-stride, 1024 blocks ----------------
// Concatenated float4 index space: X (393216) | Wq|Wk|Wv|Wo (147456 each).
__global__ __launch_bounds__(256)
void convert_all(const float* __restrict__ X,
                 const float* __restrict__ Wq, const float* __restrict__ Wk,
                 const float* __restrict__ Wv, const float* __restrict__ Wo,
                 short* __restrict__ Xb, short* __restrict__ Wqkvb,
                 short* __restrict__ Wob) {
    const int NX4 = 393216, NW4 = 147456, TOT = 983040;
    for (int idx = blockIdx.x * 256 + threadIdx.x; idx < TOT; idx += 1024 * 256) {
        const float* src; short* dst; int e;
        if (idx < NX4) {
            src = X; dst = Xb; e = idx * 4;
        } else {
            int j = idx - NX4;
            int wb = j / NW4, lb = j % NW4;
            src = wb == 0 ? Wq : wb == 1 ? Wk : wb == 2 ? Wv : Wo;
            dst = wb < 3 ? Wqkvb + wb * NW : Wob;
            e = lb * 4;
        }
        float4 v = *(const float4*)(src + e);
        *(short4*)(dst + e) = make_short4(f2b(v.x), f2b(v.y), f2b(v.z), f2b(v.w));
    }
}

// ========== bf16 GEMM, 64x64 tile, BK=64, dbuf, global_load_lds ==========
// C[m][n] = sum_k A[m][k]*B[n][k]. 32KB LDS -> 5 blocks/CU ceiling (TLP).
// 4 waves in 2x2; wave computes 32x32 (2x2 16x16 frags). XOR-swizzled LDS.
template<int OUT_BF16>
__device__ __forceinline__ void gemm64x64(const short* __restrict__ A,
    const short* __restrict__ B, void* __restrict__ Cv,
    int bm, int bn, int ldc) {
    __shared__ short sA[2][64 * 64];     // 8KB per buf
    __shared__ short sB[2][64 * 64];     // 8KB per buf  (total 32KB)

    const int tid = threadIdx.x, lane = tid & 63, w = tid >> 6;
    const int wr = w >> 1, wc = w & 1;

    f32x4 acc[2][2] = {};

    auto stage = [&](int buf, int k0) {
        #pragma unroll
        for (int c = 0; c < 2; ++c) {
            int r = w * 16 + c * 8 + (lane >> 3);
            int scb = ((lane & 7) * 16) ^ ((r & 7) << 4);
            const char* gpA = (const char*)(A + (size_t)(bm * 64 + r) * 768 + k0) + scb;
            __builtin_amdgcn_global_load_lds((gas_ptr)gpA,
                (las_ptr)((char*)&sA[buf][0] + w * 2048 + c * 1024), 16, 0, 0);
            const char* gpB = (const char*)(B + (size_t)(bn * 64 + r) * 768 + k0) + scb;
            __builtin_amdgcn_global_load_lds((gas_ptr)gpB,
                (las_ptr)((char*)&sB[buf][0] + w * 2048 + c * 1024), 16, 0, 0);
        }
    };

    stage(0, 0);
    __syncthreads();
    int cur = 0;
    for (int t = 0; t < 12; ++t) {
        if (t < 11) stage(cur ^ 1, (t + 1) * 64);
        #pragma unroll
        for (int kh = 0; kh < 2; ++kh) {
            const int kb = kh * 64 + ((lane >> 4) << 4);
            short8 av[2], bv[2];
            #pragma unroll
            for (int mi = 0; mi < 2; ++mi) {
                int row = wr * 32 + mi * 16 + (lane & 15);
                av[mi] = *(const short8*)((const char*)&sA[cur][0] + row * 128 + (kb ^ ((row & 7) << 4)));
            }
            #pragma unroll
            for (int ni = 0; ni < 2; ++ni) {
                int row = wc * 32 + ni * 16 + (lane & 15);
                bv[ni] = *(const short8*)((const char*)&sB[cur][0] + row * 128 + (kb ^ ((row & 7) << 4)));
            }
            #pragma unroll
            for (int mi = 0; mi < 2; ++mi)
                #pragma unroll
                for (int ni = 0; ni < 2; ++ni)
                    acc[mi][ni] = __builtin_amdgcn_mfma_f32_16x16x32_bf16(
                        av[mi], bv[ni], acc[mi][ni], 0, 0, 0);
        }
        __syncthreads();
        cur ^= 1;
    }

    const int crow0 = bm * 64 + wr * 32;
    const int ccol0 = bn * 64 + wc * 32;
    #pragma unroll
    for (int mi = 0; mi < 2; ++mi)
        #pragma unroll
        for (int ni = 0; ni < 2; ++ni)
            #pragma unroll
            for (int r = 0; r < 4; ++r) {
                int grow = crow0 + mi * 16 + ((lane >> 4) << 2) + r;
                int gcol = ccol0 + ni * 16 + (lane & 15);
                if (OUT_BF16)
                    ((short*)Cv)[(size_t)grow * ldc + gcol] = f2b(acc[mi][ni][r]);
                else
                    ((float*)Cv)[(size_t)grow * ldc + gcol] = acc[mi][ni][r];
            }
}

// Kernel 1: QKV = Xb @ Wqkvb^T. 32bm x 36bn = 1152 blocks (8 XCD x 144).
// 2D XCD chunk (2x4): XCD owns 16bm x 9bn -> WS = 1.5MB A + 0.9MB B.
__global__ __launch_bounds__(256)
void gemm_qkv(const short* __restrict__ Xb, const short* __restrict__ Wqkvb,
              short* __restrict__ C) {
    const int x = blockIdx.x & 7, i = blockIdx.x >> 3;   // i in [0,144)
    const int bm = (x >> 2) * 16 + i / 9;
    const int bn = (x & 3) * 9 + i % 9;
    gemm64x64<1>(Xb, Wqkvb, C, bm, bn, QKV_LD);
}

// Kernel 3: out = Attnb @ Wob^T. 32bm x 12bn = 384 blocks (8 XCD x 48).
// 2D XCD chunk (2x4): XCD owns 16bm x 3bn.
__global__ __launch_bounds__(256)
void gemm_out(const short* __restrict__ A, const short* __restrict__ Wob,
              float* __restrict__ C) {
    const int x = blockIdx.x & 7, i = blockIdx.x >> 3;   // i in [0,48)
    const int bm = (x >> 2) * 16 + i / 3;
    const int bn = (x & 3) * 3 + i % 3;
    gemm64x64<0>(A, Wob, C, bm, bn, HIDDEN);
}

// ================= Kernel 2: MFMA sliding-window attention ===================
// (exact R6-proven structure)
__global__ __launch_bounds__(256)
void attn_mfma(const short* __restrict__ QKV, short* __restrict__ O) {
    __shared__ short sK[128 * 64];       // [kt][d]  swz, 16KB
    __shared__ short sVt[64 * 128];      // [d][kt]  swz, 16KB
    __shared__ short sP[4][16 * 128];    // per-wave [q][kt] swz, 16KB

    const int bid = blockIdx.x;                 // 384 = 8*48
    const int task = (bid & 7) * 48 + (bid >> 3);
    const int h = task % NHEADS;
    const int s0 = (task / NHEADS) * 64;
    const int tid = threadIdx.x, lane = tid & 63, w = tid >> 6;

    #pragma unroll
    for (int c = 0; c < 4; ++c) {
        int r = (w * 4 + c) * 8 + (lane >> 3);
        int gr = s0 - 64 + r; if (gr < 0) gr = 0;
        int scb = ((lane & 7) * 16) ^ ((r & 7) << 4);
        const char* gp = (const char*)(QKV + (size_t)gr * QKV_LD + 768 + h * 64) + scb;
        __builtin_amdgcn_global_load_lds((gas_ptr)gp,
            (las_ptr)((char*)sK + (w * 4 + c) * 1024), 16, 0, 0);
    }
    {   // V transposed: thread = (4 keys, 8 dims) -> 8x ds_write_b64
        const int d0 = (tid & 7) * 8;
        const int kbase = (tid >> 3) * 4;
        short8 v[4];
        #pragma unroll
        for (int i = 0; i < 4; ++i) {
            int gr = s0 - 64 + kbase + i; if (gr < 0) gr = 0;
            v[i] = *(const short8*)(QKV + (size_t)gr * QKV_LD + 1536 + h * 64 + d0);
        }
        #pragma unroll
        for (int j = 0; j < 8; ++j) {
            int row = d0 + j;
            int b = row * 256 + ((kbase * 2) ^ ((row & 7) << 4));
            *(short4*)((char*)sVt + b) = make_short4(v[0][j], v[1][j], v[2][j], v[3][j]);
        }
    }
    const int qrow = w * 16 + (lane & 15);
    short8 qf[2];
    #pragma unroll
    for (int kk = 0; kk < 2; ++kk)
        qf[kk] = *(const short8*)(QKV + (size_t)(s0 + qrow) * QKV_LD + h * 64
                                  + kk * 32 + ((lane >> 4) << 3));
    __syncthreads();

    f32x4 s_acc[8];
    #pragma unroll
    for (int ct = 0; ct < 8; ++ct) {
        s_acc[ct] = (f32x4){0.f, 0.f, 0.f, 0.f};
        int krow = ct * 16 + (lane & 15);
        #pragma unroll
        for (int kk = 0; kk < 2; ++kk) {
            int cb = kk * 64 + ((lane >> 4) << 4);
            short8 kf = *(const short8*)((const char*)sK + krow * 128 + (cb ^ ((krow & 7) << 4)));
            s_acc[ct] = __builtin_amdgcn_mfma_f32_16x16x32_bf16(qf[kk], kf, s_acc[ct], 0, 0, 0);
        }
    }

    const int kcol = lane & 15;
    const int qb = w * 16 + ((lane >> 4) << 2);
    float p[8][4];
    #pragma unroll
    for (int r = 0; r < 4; ++r) {
        int q = qb + r;
        float m = -1e30f;
        #pragma unroll
        for (int ct = 0; ct < 8; ++ct) {
            int kt = ct * 16 + kcol;
            bool valid = (kt > q) && (kt <= q + 64) && (s0 + kt >= 64);
            float sc = valid ? s_acc[ct][r] * 0.125f : -1e30f;
            p[ct][r] = sc;
            m = fmaxf(m, sc);
        }
        #pragma unroll
        for (int off = 1; off < 16; off <<= 1) m = fmaxf(m, __shfl_xor(m, off));
        float sm = 0.f;
        #pragma unroll
        for (int ct = 0; ct < 8; ++ct) {
            float e = __expf(p[ct][r] - m);
            p[ct][r] = e;
            sm += e;
        }
        #pragma unroll
        for (int off = 1; off < 16; off <<= 1) sm += __shfl_xor(sm, off);
        float inv = 1.f / sm;
        #pragma unroll
        for (int ct = 0; ct < 8; ++ct) p[ct][r] *= inv;
    }

    #pragma unroll
    for (int ct = 0; ct < 8; ++ct)
        #pragma unroll
        for (int r = 0; r < 4; ++r) {
            int row = ((lane >> 4) << 2) + r;
            int b = row * 256 + (((ct * 16 + kcol) * 2) ^ ((row & 7) << 4));
            *(short*)((char*)&sP[w][0] + b) = f2b(p[ct][r]);
        }

    short8 pf[4];
    #pragma unroll
    for (int kk = 0; kk < 4; ++kk) {
        int row = lane & 15;
        int cb = kk * 64 + ((lane >> 4) << 4);
        pf[kk] = *(const short8*)((const char*)&sP[w][0] + row * 256 + (cb ^ ((row & 7) << 4)));
    }
    f32x4 o_acc[4];
    #pragma unroll
    for (int nt = 0; nt < 4; ++nt) {
        o_acc[nt] = (f32x4){0.f, 0.f, 0.f, 0.f};
        #pragma unroll
        for (int kk = 0; kk < 4; ++kk) {
            int vrow = nt * 16 + (lane & 15);
            int cb = kk * 64 + ((lane >> 4) << 4);
            short8 vf = *(const short8*)((const char*)sVt + vrow * 256 + (cb ^ ((vrow & 7) << 4)));
            o_acc[nt] = __builtin_amdgcn_mfma_f32_16x16x32_bf16(pf[kk], vf, o_acc[nt], 0, 0, 0);
        }
    }

    #pragma unroll
    for (int nt = 0; nt < 4; ++nt)
        #pragma unroll
        for (int r = 0; r < 4; ++r) {
            int q = s0 + qb + r;
            int dcol = h * 64 + nt * 16 + (lane & 15);
            O[(size_t)q * HIDDEN + dcol] = f2b(o_acc[nt][r]);
        }
}

// ---------------- launcher ----------------
extern "C" void kernel_launch(void* const* d_in, const int* in_sizes, int n_in,
                              void* d_out, int out_size, void* d_ws, size_t ws_size,
                              hipStream_t stream) {
    const float* X  = (const float*)d_in[0];
    const float* Wq = (const float*)d_in[1];
    const float* Wk = (const float*)d_in[2];
    const float* Wv = (const float*)d_in[3];
    const float* Wo = (const float*)d_in[4];
    float* out = (float*)d_out;

    char* ws = (char*)d_ws;
    short* Xb    = (short*)ws;                   // 2048*768   bf16
    short* Wqkvb = (short*)(ws + 3145728);       // 2304*768   bf16
    short* Wob   = (short*)(ws + 6684672);       // 768*768    bf16
    short* QKVb  = (short*)(ws + 7864320);       // 2048*2304  bf16
    short* Attnb = (short*)(ws + 17301504);      // 2048*768   bf16

    convert_all<<<1024, 256, 0, stream>>>(X, Wq, Wk, Wv, Wo, Xb, Wqkvb, Wob);
    gemm_qkv<<<1152, 256, 0, stream>>>(Xb, Wqkvb, QKVb);
    attn_mfma<<<384, 256, 0, stream>>>(QKVb, Attnb);
    gemm_out<<<384, 256, 0, stream>>>(Attnb, Wob, out);
}

// Round 11
// 47.641 us; speedup vs baseline: 4.6014x; 1.0455x over previous
//
#include <hip/hip_runtime.h>
#include <stdint.h>

// ---- problem constants ----
#define S_LEN   2048
#define HIDDEN  768
#define NHEADS  12
#define QKV_LD  2304   // fused q|k|v row stride (elements)
#define NW      589824 // 768*768

typedef __attribute__((ext_vector_type(8))) short short8;
typedef __attribute__((ext_vector_type(4))) float f32x4;

typedef const __attribute__((address_space(1))) void* gas_ptr;
typedef __attribute__((address_space(3))) void* las_ptr;

__device__ __forceinline__ short f2b(float f) {
    union { float f; uint32_t u; } v; v.f = f;
    uint32_t u = v.u;
    uint32_t r = (u + 0x7FFFu + ((u >> 16) & 1u)) >> 16;
    return (short)r;
}

// ---------------- f32 -> bf16 converts: grid-stride, 1024 blocks ----------------
// (R10-proven: ~6us, near HBM floor)
__global__ __launch_bounds__(256)
void convert_all(const float* __restrict__ X,
                 const float* __restrict__ Wq, const float* __restrict__ Wk,
                 const float* __restrict__ Wv, const float* __restrict__ Wo,
                 short* __restrict__ Xb, short* __restrict__ Wqkvb,
                 short* __restrict__ Wob) {
    const int NX4 = 393216, NW4 = 147456, TOT = 983040;
    for (int idx = blockIdx.x * 256 + threadIdx.x; idx < TOT; idx += 1024 * 256) {
        const float* src; short* dst; int e;
        if (idx < NX4) {
            src = X; dst = Xb; e = idx * 4;
        } else {
            int j = idx - NX4;
            int wb = j / NW4, lb = j % NW4;
            src = wb == 0 ? Wq : wb == 1 ? Wk : wb == 2 ? Wv : Wo;
            dst = wb < 3 ? Wqkvb + wb * NW : Wob;
            e = lb * 4;
        }
        float4 v = *(const float4*)(src + e);
        *(short4*)(dst + e) = make_short4(f2b(v.x), f2b(v.y), f2b(v.z), f2b(v.w));
    }
}

// ========== bf16 GEMM, 64x128 tile, BK=64, dbuf, global_load_lds ==========
// (exact R6-proven structure: 47.6us baseline's GEMM)
template<int OUT_BF16>
__device__ __forceinline__ void gemm64x128(const short* __restrict__ A,
    const short* __restrict__ B, void* __restrict__ Cv,
    int bm, int bn, int ldc) {
    __shared__ short sA[2][64 * 64];     // 8KB per buf
    __shared__ short sB[2][128 * 64];    // 16KB per buf  (total 48KB)

    const int tid = threadIdx.x, lane = tid & 63, w = tid >> 6;
    const int wr = w >> 1, wc = w & 1;

    f32x4 acc[2][4] = {};

    auto stage = [&](int buf, int k0) {
        #pragma unroll
        for (int c = 0; c < 2; ++c) {
            int r = w * 16 + c * 8 + (lane >> 3);
            int scb = ((lane & 7) * 16) ^ ((r & 7) << 4);
            const char* gp = (const char*)(A + (size_t)(bm * 64 + r) * 768 + k0) + scb;
            __builtin_amdgcn_global_load_lds((gas_ptr)gp,
                (las_ptr)((char*)&sA[buf][0] + w * 2048 + c * 1024), 16, 0, 0);
        }
        #pragma unroll
        for (int c = 0; c < 4; ++c) {
            int r = w * 32 + c * 8 + (lane >> 3);
            int scb = ((lane & 7) * 16) ^ ((r & 7) << 4);
            const char* gp = (const char*)(B + (size_t)(bn * 128 + r) * 768 + k0) + scb;
            __builtin_amdgcn_global_load_lds((gas_ptr)gp,
                (las_ptr)((char*)&sB[buf][0] + w * 4096 + c * 1024), 16, 0, 0);
        }
    };

    stage(0, 0);
    __syncthreads();
    int cur = 0;
    for (int t = 0; t < 12; ++t) {
        if (t < 11) stage(cur ^ 1, (t + 1) * 64);
        #pragma unroll
        for (int kh = 0; kh < 2; ++kh) {
            const int kb = kh * 64 + ((lane >> 4) << 4);
            short8 av[2], bv[4];
            #pragma unroll
            for (int mi = 0; mi < 2; ++mi) {
                int row = wr * 32 + mi * 16 + (lane & 15);
                av[mi] = *(const short8*)((const char*)&sA[cur][0] + row * 128 + (kb ^ ((row & 7) << 4)));
            }
            #pragma unroll
            for (int ni = 0; ni < 4; ++ni) {
                int row = wc * 64 + ni * 16 + (lane & 15);
                bv[ni] = *(const short8*)((const char*)&sB[cur][0] + row * 128 + (kb ^ ((row & 7) << 4)));
            }
            #pragma unroll
            for (int mi = 0; mi < 2; ++mi)
                #pragma unroll
                for (int ni = 0; ni < 4; ++ni)
                    acc[mi][ni] = __builtin_amdgcn_mfma_f32_16x16x32_bf16(
                        av[mi], bv[ni], acc[mi][ni], 0, 0, 0);
        }
        __syncthreads();
        cur ^= 1;
    }

    const int crow0 = bm * 64 + wr * 32;
    const int ccol0 = bn * 128 + wc * 64;
    #pragma unroll
    for (int mi = 0; mi < 2; ++mi)
        #pragma unroll
        for (int ni = 0; ni < 4; ++ni)
            #pragma unroll
            for (int r = 0; r < 4; ++r) {
                int grow = crow0 + mi * 16 + ((lane >> 4) << 2) + r;
                int gcol = ccol0 + ni * 16 + (lane & 15);
                if (OUT_BF16)
                    ((short*)Cv)[(size_t)grow * ldc + gcol] = f2b(acc[mi][ni][r]);
                else
                    ((float*)Cv)[(size_t)grow * ldc + gcol] = acc[mi][ni][r];
            }
}

// Kernel 1: QKV = Xb @ Wqkvb^T. M=2048,N=2304 -> 32x18 = 576 blocks (8*72).
__global__ __launch_bounds__(256)
void gemm_qkv(const short* __restrict__ Xb, const short* __restrict__ Wqkvb,
              short* __restrict__ C) {
    const int bid = blockIdx.x;
    const int sw = (bid & 7) * 72 + (bid >> 3);   // bijective XCD chunking
    gemm64x128<1>(Xb, Wqkvb, C, sw / 18, sw % 18, QKV_LD);
}

// Kernel 3: out = Attnb @ Wob^T. M=2048,N=768 -> 32x6 = 192 blocks (8*24).
__global__ __launch_bounds__(256)
void gemm_out(const short* __restrict__ A, const short* __restrict__ Wob,
              float* __restrict__ C) {
    const int bid = blockIdx.x;
    const int sw = (bid & 7) * 24 + (bid >> 3);
    gemm64x128<0>(A, Wob, C, sw / 6, sw % 6, HIDDEN);
}

// ================= Kernel 2: MFMA sliding-window attention ===================
// (exact R6-proven structure)
__global__ __launch_bounds__(256)
void attn_mfma(const short* __restrict__ QKV, short* __restrict__ O) {
    __shared__ short sK[128 * 64];       // [kt][d]  swz, 16KB
    __shared__ short sVt[64 * 128];      // [d][kt]  swz, 16KB
    __shared__ short sP[4][16 * 128];    // per-wave [q][kt] swz, 16KB

    const int bid = blockIdx.x;                 // 384 = 8*48
    const int task = (bid & 7) * 48 + (bid >> 3);
    const int h = task % NHEADS;
    const int s0 = (task / NHEADS) * 64;
    const int tid = threadIdx.x, lane = tid & 63, w = tid >> 6;

    #pragma unroll
    for (int c = 0; c < 4; ++c) {
        int r = (w * 4 + c) * 8 + (lane >> 3);
        int gr = s0 - 64 + r; if (gr < 0) gr = 0;
        int scb = ((lane & 7) * 16) ^ ((r & 7) << 4);
        const char* gp = (const char*)(QKV + (size_t)gr * QKV_LD + 768 + h * 64) + scb;
        __builtin_amdgcn_global_load_lds((gas_ptr)gp,
            (las_ptr)((char*)sK + (w * 4 + c) * 1024), 16, 0, 0);
    }
    {   // V transposed: thread = (4 keys, 8 dims) -> 8x ds_write_b64
        const int d0 = (tid & 7) * 8;
        const int kbase = (tid >> 3) * 4;
        short8 v[4];
        #pragma unroll
        for (int i = 0; i < 4; ++i) {
            int gr = s0 - 64 + kbase + i; if (gr < 0) gr = 0;
            v[i] = *(const short8*)(QKV + (size_t)gr * QKV_LD + 1536 + h * 64 + d0);
        }
        #pragma unroll
        for (int j = 0; j < 8; ++j) {
            int row = d0 + j;
            int b = row * 256 + ((kbase * 2) ^ ((row & 7) << 4));
            *(short4*)((char*)sVt + b) = make_short4(v[0][j], v[1][j], v[2][j], v[3][j]);
        }
    }
    const int qrow = w * 16 + (lane & 15);
    short8 qf[2];
    #pragma unroll
    for (int kk = 0; kk < 2; ++kk)
        qf[kk] = *(const short8*)(QKV + (size_t)(s0 + qrow) * QKV_LD + h * 64
                                  + kk * 32 + ((lane >> 4) << 3));
    __syncthreads();

    f32x4 s_acc[8];
    #pragma unroll
    for (int ct = 0; ct < 8; ++ct) {
        s_acc[ct] = (f32x4){0.f, 0.f, 0.f, 0.f};
        int krow = ct * 16 + (lane & 15);
        #pragma unroll
        for (int kk = 0; kk < 2; ++kk) {
            int cb = kk * 64 + ((lane >> 4) << 4);
            short8 kf = *(const short8*)((const char*)sK + krow * 128 + (cb ^ ((krow & 7) << 4)));
            s_acc[ct] = __builtin_amdgcn_mfma_f32_16x16x32_bf16(qf[kk], kf, s_acc[ct], 0, 0, 0);
        }
    }

    const int kcol = lane & 15;
    const int qb = w * 16 + ((lane >> 4) << 2);
    float p[8][4];
    #pragma unroll
    for (int r = 0; r < 4; ++r) {
        int q = qb + r;
        float m = -1e30f;
        #pragma unroll
        for (int ct = 0; ct < 8; ++ct) {
            int kt = ct * 16 + kcol;
            bool valid = (kt > q) && (kt <= q + 64) && (s0 + kt >= 64);
            float sc = valid ? s_acc[ct][r] * 0.125f : -1e30f;
            p[ct][r] = sc;
            m = fmaxf(m, sc);
        }
        #pragma unroll
        for (int off = 1; off < 16; off <<= 1) m = fmaxf(m, __shfl_xor(m, off));
        float sm = 0.f;
        #pragma unroll
        for (int ct = 0; ct < 8; ++ct) {
            float e = __expf(p[ct][r] - m);
            p[ct][r] = e;
            sm += e;
        }
        #pragma unroll
        for (int off = 1; off < 16; off <<= 1) sm += __shfl_xor(sm, off);
        float inv = 1.f / sm;
        #pragma unroll
        for (int ct = 0; ct < 8; ++ct) p[ct][r] *= inv;
    }

    #pragma unroll
    for (int ct = 0; ct < 8; ++ct)
        #pragma unroll
        for (int r = 0; r < 4; ++r) {
            int row = ((lane >> 4) << 2) + r;
            int b = row * 256 + (((ct * 16 + kcol) * 2) ^ ((row & 7) << 4));
            *(short*)((char*)&sP[w][0] + b) = f2b(p[ct][r]);
        }

    short8 pf[4];
    #pragma unroll
    for (int kk = 0; kk < 4; ++kk) {
        int row = lane & 15;
        int cb = kk * 64 + ((lane >> 4) << 4);
        pf[kk] = *(const short8*)((const char*)&sP[w][0] + row * 256 + (cb ^ ((row & 7) << 4)));
    }
    f32x4 o_acc[4];
    #pragma unroll
    for (int nt = 0; nt < 4; ++nt) {
        o_acc[nt] = (f32x4){0.f, 0.f, 0.f, 0.f};
        #pragma unroll
        for (int kk = 0; kk < 4; ++kk) {
            int vrow = nt * 16 + (lane & 15);
            int cb = kk * 64 + ((lane >> 4) << 4);
            short8 vf = *(const short8*)((const char*)sVt + vrow * 256 + (cb ^ ((vrow & 7) << 4)));
            o_acc[nt] = __builtin_amdgcn_mfma_f32_16x16x32_bf16(pf[kk], vf, o_acc[nt], 0, 0, 0);
        }
    }

    #pragma unroll
    for (int nt = 0; nt < 4; ++nt)
        #pragma unroll
        for (int r = 0; r < 4; ++r) {
            int q = s0 + qb + r;
            int dcol = h * 64 + nt * 16 + (lane & 15);
            O[(size_t)q * HIDDEN + dcol] = f2b(o_acc[nt][r]);
        }
}

// ---------------- launcher ----------------
extern "C" void kernel_launch(void* const* d_in, const int* in_sizes, int n_in,
                              void* d_out, int out_size, void* d_ws, size_t ws_size,
                              hipStream_t stream) {
    const float* X  = (const float*)d_in[0];
    const float* Wq = (const float*)d_in[1];
    const float* Wk = (const float*)d_in[2];
    const float* Wv = (const float*)d_in[3];
    const float* Wo = (const float*)d_in[4];
    float* out = (float*)d_out;

    char* ws = (char*)d_ws;
    short* Xb    = (short*)ws;                   // 2048*768   bf16
    short* Wqkvb = (short*)(ws + 3145728);       // 2304*768   bf16
    short* Wob   = (short*)(ws + 6684672);       // 768*768    bf16
    short* QKVb  = (short*)(ws + 7864320);       // 2048*2304  bf16
    short* Attnb = (short*)(ws + 17301504);      // 2048*768   bf16

    convert_all<<<1024, 256, 0, stream>>>(X, Wq, Wk, Wv, Wo, Xb, Wqkvb, Wob);
    gemm_qkv<<<576, 256, 0, stream>>>(Xb, Wqkvb, QKVb);
    attn_mfma<<<384, 256, 0, stream>>>(QKVb, Attnb);
    gemm_out<<<192, 256, 0, stream>>>(Attnb, Wob, out);
}